// Round 3
// baseline (16.706 us; speedup 1.0000x reference)
//
#include <hip/hip_runtime.h>

// MultiScaleHead: B=16, L=2048, H=1024, P=16, S=128
#define B_ 16
#define L_ 2048
#define H_ 1024
#define P_ 16
#define S_ 128

// Kernel 1: per-(b,s) scalar weights into d_ws; out = bias.
__global__ void __launch_bounds__(128) msh_init(
        const int* __restrict__ par_head,
        const int* __restrict__ par_tail,
        const int* __restrict__ sent_head,
        const float* __restrict__ bias,
        float* __restrict__ w_out,
        float* __restrict__ out) {
    int b = blockIdx.x;
    int t = threadIdx.x;  // 0..127

    __shared__ int   sh[S_];
    __shared__ float inv_scnt[P_];
    __shared__ int   validp[P_];
    __shared__ float invpar;

    sh[t] = sent_head[b * S_ + t];
    __syncthreads();

    // 2 waves; wave w handles paragraphs p = w*8 .. w*8+7 (serial over 8),
    // each paragraph's count reduced across the 64-lane wave (2 sentences/lane).
    {
        int wave = t >> 6, lane = t & 63;
        for (int k = 0; k < 8; ++k) {
            int p = wave * 8 + k;
            int h0 = par_head[b * P_ + p];
            int t0 = par_tail[b * P_ + p];
            int s1 = lane, s2 = lane + 64;
            int in1 = (h0 <= sh[s1]) && (sh[s1] <= t0);
            int in2 = (h0 <= sh[s2]) && (sh[s2] <= t0);
            int cnt = in1 + in2;
            int nz  = (in1 && sh[s1] != 0) || (in2 && sh[s2] != 0);
            for (int off = 32; off > 0; off >>= 1) {
                cnt += __shfl_down(cnt, off, 64);
                nz  |= __shfl_down(nz,  off, 64);
            }
            if (lane == 0) {
                int valid = ((t0 - h0) > 2) && nz;
                validp[p] = valid;
                inv_scnt[p] = valid ? 1.0f / (float)(cnt > 1 ? cnt : 1) : 0.0f;
            }
        }
    }
    __syncthreads();
    if (t == 0) {
        int pc = 0;
        for (int p = 0; p < P_; ++p) pc += validp[p];
        invpar = 1.0f / (float)(pc > 1 ? pc : 1);
    }
    __syncthreads();

    int myh = sh[t];
    float w = 0.0f;
    for (int p = 0; p < P_; ++p) {
        int h0 = par_head[b * P_ + p];
        int t0 = par_tail[b * P_ + p];
        if (h0 <= myh && myh <= t0) w += inv_scnt[p];
    }
    w_out[b * S_ + t] = w * invpar;

    if (t < 5) out[b * 5 + t] = bias[t];
}

// Kernel 2: 16 blocks per batch, 8 sentences each, 256 threads (H float4).
// Partial 5-dot per block -> atomicAdd into out (bias already there).
__global__ void __launch_bounds__(256) msh_main(
        const float* __restrict__ backbone,
        const int* __restrict__ sent_head,
        const float* __restrict__ W,
        const float* __restrict__ wgt,
        float* __restrict__ out) {
    int blk = blockIdx.x;
    int b   = blk >> 4;
    int sub = blk & 15;
    int t   = threadIdx.x;   // 0..255, one float4 slot of H

    const float4* bb4 = reinterpret_cast<const float4*>(
        backbone + (size_t)b * L_ * H_);

    float4 acc = make_float4(0.f, 0.f, 0.f, 0.f);
    int s0 = sub * 8;
#pragma unroll
    for (int i = 0; i < 8; ++i) {
        int s = s0 + i;
        float w = wgt[b * S_ + s];
        if (w != 0.0f) {                       // block-uniform branch
            int row = sent_head[b * S_ + s];
            float4 v = bb4[(size_t)row * (H_ / 4) + t];
            acc.x += w * v.x; acc.y += w * v.y;
            acc.z += w * v.z; acc.w += w * v.w;
        }
    }

    const float4* W4 = reinterpret_cast<const float4*>(W);
    float pj[5];
#pragma unroll
    for (int j = 0; j < 5; ++j) {
        float4 wv = W4[j * (H_ / 4) + t];
        pj[j] = acc.x * wv.x + acc.y * wv.y + acc.z * wv.z + acc.w * wv.w;
    }

    int wave = t >> 6, lane = t & 63;
#pragma unroll
    for (int j = 0; j < 5; ++j) {
        float v = pj[j];
        for (int off = 32; off > 0; off >>= 1) v += __shfl_down(v, off, 64);
        pj[j] = v;
    }

    __shared__ float red[4][5];
    if (lane == 0) {
#pragma unroll
        for (int j = 0; j < 5; ++j) red[wave][j] = pj[j];
    }
    __syncthreads();

    if (t < 5) {
        float tot = red[0][t] + red[1][t] + red[2][t] + red[3][t];
        atomicAdd(out + b * 5 + t, tot);
    }
}

extern "C" void kernel_launch(void* const* d_in, const int* in_sizes, int n_in,
                              void* d_out, int out_size, void* d_ws, size_t ws_size,
                              hipStream_t stream) {
    const float* backbone  = (const float*)d_in[0];
    // d_in[1] = attention_mask (unused by reference)
    const int*   par_head  = (const int*)d_in[2];
    const int*   par_tail  = (const int*)d_in[3];
    // d_in[4] = paragraph_attention_mask (unused)
    const int*   sent_head = (const int*)d_in[5];
    // d_in[6] = sentence_tail_idxs (unused), d_in[7] = sentence_attention_mask (unused)
    const float* W         = (const float*)d_in[8];
    const float* bias      = (const float*)d_in[9];

    float* out  = (float*)d_out;
    float* w_ws = (float*)d_ws;   // B_*S_ floats = 8 KB

    msh_init<<<B_, 128, 0, stream>>>(par_head, par_tail, sent_head, bias, w_ws, out);
    msh_main<<<B_ * 16, 256, 0, stream>>>(backbone, sent_head, W, w_ws, out);
}

// Round 4
// 12.372 us; speedup vs baseline: 1.3503x; 1.3503x over previous
//
#include <hip/hip_runtime.h>

// MultiScaleHead: B=16, L=2048, H=1024, P=16, S=128
#define B_ 16
#define L_ 2048
#define H_ 1024
#define P_ 16
#define S_ 128

// Single fused kernel, one block per batch, 1024 threads (16 waves).
// out[b,j] = sum_s w[b,s] * dot(backbone[b, sent_head[b,s], :], W[j,:]) + bias[j]
// Structure: prefetch row/W loads first, overlap weights computation with
// load latency, then weighted accumulate + 5 dots + block reduce.
__global__ void __launch_bounds__(1024) msh_fused(
        const float* __restrict__ backbone,
        const int* __restrict__ par_head,
        const int* __restrict__ par_tail,
        const int* __restrict__ sent_head,
        const float* __restrict__ W,
        const float* __restrict__ bias,
        float* __restrict__ out) {
    int b = blockIdx.x;
    int t = threadIdx.x;
    int wave = t >> 6, lane = t & 63;
    int grp = t >> 8, q = t & 255;      // 4 sentence-groups x 256 H-slots

    __shared__ int   sh[S_];
    __shared__ int   ph[P_], pt[P_];
    __shared__ float inv_scnt[P_];
    __shared__ int   validp[P_];
    __shared__ float wgt[S_];
    __shared__ float red[16][5];

    if (t < S_) sh[t] = sent_head[b * S_ + t];
    if (t < P_) { ph[t] = par_head[b * P_ + t]; pt[t] = par_tail[b * P_ + t]; }
    __syncthreads();

    // ---- Issue long-latency loads EARLY (depend only on sh) ----
    const float4* bb4 = reinterpret_cast<const float4*>(
        backbone + (size_t)b * L_ * H_);
    // first 8 rows of this thread's group: s = grp + 4*i, i=0..7
    float4 v0 = bb4[(size_t)sh[grp +  0] * (H_/4) + q];
    float4 v1 = bb4[(size_t)sh[grp +  4] * (H_/4) + q];
    float4 v2 = bb4[(size_t)sh[grp +  8] * (H_/4) + q];
    float4 v3 = bb4[(size_t)sh[grp + 12] * (H_/4) + q];
    float4 v4 = bb4[(size_t)sh[grp + 16] * (H_/4) + q];
    float4 v5 = bb4[(size_t)sh[grp + 20] * (H_/4) + q];
    float4 v6 = bb4[(size_t)sh[grp + 24] * (H_/4) + q];
    float4 v7 = bb4[(size_t)sh[grp + 28] * (H_/4) + q];
    // W rows (L2-resident)
    const float4* W4 = reinterpret_cast<const float4*>(W);
    float4 wj0 = W4[0 * (H_/4) + q];
    float4 wj1 = W4[1 * (H_/4) + q];
    float4 wj2 = W4[2 * (H_/4) + q];
    float4 wj3 = W4[3 * (H_/4) + q];
    float4 wj4 = W4[4 * (H_/4) + q];

    // ---- Weights: wave p handles paragraph p (16 waves, 16 paragraphs) ----
    {
        int p  = wave;
        int h0 = ph[p], t0 = pt[p];
        int s1 = lane, s2 = lane + 64;
        int in1 = (h0 <= sh[s1]) && (sh[s1] <= t0);
        int in2 = (h0 <= sh[s2]) && (sh[s2] <= t0);
        int cnt = in1 + in2;
        int nz  = (in1 && sh[s1] != 0) || (in2 && sh[s2] != 0);
        for (int off = 32; off > 0; off >>= 1) {
            cnt += __shfl_down(cnt, off, 64);
            nz  |= __shfl_down(nz,  off, 64);
        }
        if (lane == 0) {
            int valid = ((t0 - h0) > 2) && nz;
            validp[p] = valid;
            inv_scnt[p] = valid ? 1.0f / (float)(cnt > 1 ? cnt : 1) : 0.0f;
        }
    }
    __syncthreads();
    if (t < S_) {
        int myh = sh[t];
        float w = 0.0f; int pc = 0;
        for (int p = 0; p < P_; ++p) {
            pc += validp[p];
            if (ph[p] <= myh && myh <= pt[p]) w += inv_scnt[p];
        }
        wgt[t] = w / (float)(pc > 1 ? pc : 1);
    }
    __syncthreads();

    // ---- Weighted accumulate: prefetched rows first ----
    float4 acc = make_float4(0.f, 0.f, 0.f, 0.f);
#define FMA4(wv, v) do { float _w = (wv); \
        acc.x += _w * (v).x; acc.y += _w * (v).y; \
        acc.z += _w * (v).z; acc.w += _w * (v).w; } while (0)
    FMA4(wgt[grp +  0], v0);
    FMA4(wgt[grp +  4], v1);
    FMA4(wgt[grp +  8], v2);
    FMA4(wgt[grp + 12], v3);
    FMA4(wgt[grp + 16], v4);
    FMA4(wgt[grp + 20], v5);
    FMA4(wgt[grp + 24], v6);
    FMA4(wgt[grp + 28], v7);
    // remaining 24 sentences, deep unroll for load ILP
#pragma unroll 8
    for (int s = grp + 32; s < S_; s += 4) {
        float w = wgt[s];
        float4 v = bb4[(size_t)sh[s] * (H_/4) + q];
        FMA4(w, v);
    }
#undef FMA4

    // ---- 5 dot products + block reduction ----
    float pj[5];
    pj[0] = acc.x*wj0.x + acc.y*wj0.y + acc.z*wj0.z + acc.w*wj0.w;
    pj[1] = acc.x*wj1.x + acc.y*wj1.y + acc.z*wj1.z + acc.w*wj1.w;
    pj[2] = acc.x*wj2.x + acc.y*wj2.y + acc.z*wj2.z + acc.w*wj2.w;
    pj[3] = acc.x*wj3.x + acc.y*wj3.y + acc.z*wj3.z + acc.w*wj3.w;
    pj[4] = acc.x*wj4.x + acc.y*wj4.y + acc.z*wj4.z + acc.w*wj4.w;
#pragma unroll
    for (int j = 0; j < 5; ++j) {
        float v = pj[j];
        for (int off = 32; off > 0; off >>= 1) v += __shfl_down(v, off, 64);
        pj[j] = v;
    }
    if (lane == 0) {
#pragma unroll
        for (int j = 0; j < 5; ++j) red[wave][j] = pj[j];
    }
    __syncthreads();

    if (t < 5) {
        float tot = 0.0f;
#pragma unroll
        for (int i = 0; i < 16; ++i) tot += red[i][t];
        out[b * 5 + t] = tot + bias[t];
    }
}

extern "C" void kernel_launch(void* const* d_in, const int* in_sizes, int n_in,
                              void* d_out, int out_size, void* d_ws, size_t ws_size,
                              hipStream_t stream) {
    const float* backbone  = (const float*)d_in[0];
    // d_in[1] = attention_mask (unused by reference)
    const int*   par_head  = (const int*)d_in[2];
    const int*   par_tail  = (const int*)d_in[3];
    // d_in[4] = paragraph_attention_mask (unused)
    const int*   sent_head = (const int*)d_in[5];
    // d_in[6] = sentence_tail_idxs (unused), d_in[7] = sentence_attention_mask (unused)
    const float* W         = (const float*)d_in[8];
    const float* bias      = (const float*)d_in[9];

    float* out = (float*)d_out;

    msh_fused<<<B_, 1024, 0, stream>>>(backbone, par_head, par_tail, sent_head,
                                       W, bias, out);
}